// Round 11
// baseline (232.305 us; speedup 1.0000x reference)
//
#include <hip/hip_runtime.h>
#include <hip/hip_bf16.h>

typedef short bf8 __attribute__((ext_vector_type(8)));   // 8 bf16 (4 VGPRs)
typedef float f4 __attribute__((ext_vector_type(4)));
typedef const __attribute__((address_space(1))) void* gvp;
typedef __attribute__((address_space(3))) void* lvp;

#define S_LEN 4096
#define H_DIM 1024
#define D_DIM 512
#define B_DIM 16
#define OUT_BASE ((size_t)B_DIM * S_LEN * H_DIM)

// float -> bf16 bits, round-to-nearest-even
static __device__ __forceinline__ unsigned short f2bf(float f) {
    union { float f; unsigned int u; } c; c.f = f;
    unsigned int u = c.u;
    return (unsigned short)((u + 0x7FFFu + ((u >> 16) & 1u)) >> 16);
}

// cW1 [K=1024][N=512] f32 -> wT[n][chunk 0..31][slot 0..3] bf16 (pitch 2048 B),
// PRE-SWIZZLED: slot sl holds k-slot j = sl ^ ((n>>1)&3). GEMM's linear global_load_lds
// + swizzled ds_read (slot = lg ^ ((la>>1)&3)) recovers k-slot lg; 2-way-bank (free).
__global__ __launch_bounds__(256) void prep_transpose(const float* __restrict__ cW1,
                                                      unsigned short* __restrict__ wT) {
    __shared__ float tile[64][68];
    const int kt = blockIdx.x >> 3;   // 16 tiles of 64 k
    const int nt = blockIdx.x & 7;    // 8 tiles of 64 n
    const int tr = threadIdx.x >> 4;
    const int tc = threadIdx.x & 15;
#pragma unroll
    for (int i = 0; i < 4; ++i) {
        const f4 v = *(const f4*)(cW1 + (size_t)(kt * 64 + i * 16 + tr) * D_DIM + nt * 64 + tc * 4);
        tile[i * 16 + tr][tc * 4 + 0] = v.x;
        tile[i * 16 + tr][tc * 4 + 1] = v.y;
        tile[i * 16 + tr][tc * 4 + 2] = v.z;
        tile[i * 16 + tr][tc * 4 + 3] = v.w;
    }
    __syncthreads();
    const int n_local = threadIdx.x & 63;
    const int q = threadIdx.x >> 6;        // slot 0..3
    const int n = nt * 64 + n_local;
    const int j = q ^ ((n >> 1) & 3);      // data k-slot stored at slot q
    char* wTb = (char*)wT;
#pragma unroll
    for (int c_local = 0; c_local < 2; ++c_local) {   // two 32-k chunks per 64k tile
        const int k0 = c_local * 32 + j * 8;
        bf8 pk;
#pragma unroll
        for (int i = 0; i < 8; ++i) pk[i] = (short)f2bf(tile[k0 + i][n_local]);
        *(bf8*)(wTb + (size_t)n * 2048 + (kt * 2 + c_local) * 64 + q * 16) = pk;
    }
}

// Fused stream+GEMM, 256 threads (4 waves), M=64 (one b, 64 s) x N=256 (half of D),
// BK=32 (32 chunks). LDS 40 KB (B dbuf 32 KB + A dbuf 8 KB) -> 4 blocks/CU: four
// independent barrier groups per CU hide each other's stalls. The states-copy is fused
// into A staging: threads t..t+3 cover one 128-B line of one row -> coalesced nt-stores
// (no write amplification, unlike per-lane fragment stores). Counted vmcnt(4) per chunk:
// queue [2 st_prev, 4 glB, 2 glA_next, 2 st] -> retires stores+B, keeps prefetch flying.
// Writes raw pre-sigmoid half-logits (N-half per block); reduce_comp combines halves.
__global__ __launch_bounds__(256, 4) void comp_gemm_kernel(
    const float* __restrict__ states,
    const unsigned short* __restrict__ wT,
    const float* __restrict__ cb1,
    const float* __restrict__ cW2,
    float* __restrict__ out,
    float* __restrict__ part_ws) {
    __shared__ alignas(16) char lds[40960];   // B [2][256][64] @0, A [2][64][64] @32768
    char* ldsB = lds;
    char* ldsA = lds + 32768;

    const int t = threadIdx.x;
    const int lane = t & 63;
    const int wv = t >> 6;                // 0..3 : n-slice [wv*64, +64)
    const int la = lane & 15;
    const int lg = lane >> 4;
    const int gid = blockIdx.x;
    const int b = gid >> 7;               // 16 b
    const int rem = gid & 127;
    const int s0 = (rem >> 1) * 64;       // 64 s-tiles
    const int nblk = rem & 1;             // 2 N-halves
    const int n0 = nblk * 256;

    // ---- A staging / fused copy-out: thread -> (row = t>>2, kq = t&3); threads
    // t..t+3 cover 128 contiguous bytes of one row (full-line coalesced stores) ----
    const int arow = t >> 2;
    const int kq = t & 3;
    const size_t abase = ((size_t)b * S_LEN + s0 + arow) * H_DIM + kq * 8;
    const float* srcA = states + abase;
    float* dstO = out + abase;
    char* dstA = ldsA + arow * 64 + ((kq ^ ((arow >> 2) & 3)) * 16);

    // ---- B staging: 4 x global_load_lds(16B/lane)/chunk; linear dest, swizzled src ----
    const char* srcB = (const char*)wT + (size_t)(n0 + (t >> 2)) * 2048 + (t & 3) * 16;
    char* dstB = ldsB + t * 16;

    // ---- fragment read bases (both 2-way-bank, free) ----
    const char* brd = ldsB + (wv * 64 + la) * 64 + ((lg ^ ((la >> 1) & 3)) * 16);
    const char* ard = ldsA + la * 64 + ((lg ^ ((la >> 2) & 3)) * 16);

    f4 acc[4][4];
#pragma unroll
    for (int a = 0; a < 4; ++a)
#pragma unroll
        for (int c = 0; c < 4; ++c) acc[a][c] = f4{0.f, 0.f, 0.f, 0.f};

    auto issueB = [&](int buf_, int ck_) {
#pragma unroll
        for (int i = 0; i < 4; ++i)
            __builtin_amdgcn_global_load_lds((gvp)(srcB + (size_t)i * 64 * 2048 + ck_ * 64),
                                             (lvp)(dstB + buf_ * 16384 + i * 4096), 16, 0, 0);
    };
    auto writeA = [&](int buf_, const f4 a0, const f4 a1) {
        bf8 pk;
        pk[0] = (short)f2bf(a0.x); pk[1] = (short)f2bf(a0.y);
        pk[2] = (short)f2bf(a0.z); pk[3] = (short)f2bf(a0.w);
        pk[4] = (short)f2bf(a1.x); pk[5] = (short)f2bf(a1.y);
        pk[6] = (short)f2bf(a1.z); pk[7] = (short)f2bf(a1.w);
        *(bf8*)(dstA + buf_ * 4096) = pk;
    };
    auto storeO = [&](int ck_, const f4 a0, const f4 a1) {
        __builtin_nontemporal_store(a0, (f4*)(dstO + ck_ * 32));
        __builtin_nontemporal_store(a1, (f4*)(dstO + ck_ * 32 + 4));
    };

    // ---- prologue: A(0)+B(0) -> buf0; A(1) in regs; store out A(0) ----
    f4 qa0 = *(const f4*)(srcA);
    f4 qa1 = *(const f4*)(srcA + 4);
    issueB(0, 0);
    f4 qn0 = *(const f4*)(srcA + 32);
    f4 qn1 = *(const f4*)(srcA + 36);
    writeA(0, qa0, qa1);                 // pack waits A(0) loads only
    storeO(0, qa0, qa1);
    // outstanding: [4 glB, 2 glA(1), 2 st] -> vmcnt(4) retires glB
    asm volatile("s_waitcnt vmcnt(4) lgkmcnt(0)" ::: "memory");
    __builtin_amdgcn_sched_barrier(0);
    __builtin_amdgcn_s_barrier();
    __builtin_amdgcn_sched_barrier(0);
    qa0 = qn0; qa1 = qn1;

#pragma unroll 1
    for (int ck = 0; ck < 32; ++ck) {
        const int buf = ck & 1;
        if (ck < 31) {
            writeA(buf ^ 1, qa0, qa1);                  // stage A(ck+1) (waits its loads)
            issueB(buf ^ 1, ck + 1);                    // 4 glds -> other buffer
            if (ck < 30) {
                qn0 = *(const f4*)(srcA + (ck + 2) * 32);   // A(ck+2) prefetch
                qn1 = *(const f4*)(srcA + (ck + 2) * 32 + 4);
            }
            storeO(ck + 1, qa0, qa1);                   // fused copy-out of A(ck+1)
            __builtin_amdgcn_sched_barrier(0);
        }
        // compute chunk ck from buf
        bf8 af[4];
#pragma unroll
        for (int fr = 0; fr < 4; ++fr)
            af[fr] = *(const bf8*)(ard + buf * 4096 + fr * 1024);
#pragma unroll
        for (int fc = 0; fc < 4; ++fc) {
            const bf8 bv = *(const bf8*)(brd + buf * 16384 + fc * 1024);
#pragma unroll
            for (int fr = 0; fr < 4; ++fr)
                acc[fr][fc] = __builtin_amdgcn_mfma_f32_16x16x32_bf16(af[fr], bv, acc[fr][fc], 0, 0, 0);
        }
        if (ck < 31) {
            // queue: [2 st_prev, 4 glB, (2 glA), 2 st] -> retire stores+B exactly
            if (ck < 30) { asm volatile("s_waitcnt vmcnt(4) lgkmcnt(0)" ::: "memory"); }
            else         { asm volatile("s_waitcnt vmcnt(2) lgkmcnt(0)" ::: "memory"); }
            __builtin_amdgcn_sched_barrier(0);
            __builtin_amdgcn_s_barrier();
            __builtin_amdgcn_sched_barrier(0);
            if (ck < 30) { qa0 = qn0; qa1 = qn1; }
        }
    }

    // ---- epilogue: relu + dot(cW2-half) -> raw half-logit per (b,s) ----
    float w2v[4], b1v[4];
#pragma unroll
    for (int fc = 0; fc < 4; ++fc) {
        const int d = n0 + wv * 64 + fc * 16 + la;
        w2v[fc] = cW2[d];
        b1v[fc] = cb1[d];
    }
    float* part = (float*)ldsA;   // [64 rows][4 wv] overlays A-buf0 (dead after ck30 barrier)
#pragma unroll
    for (int fr = 0; fr < 4; ++fr) {
#pragma unroll
        for (int rg = 0; rg < 4; ++rg) {
            float p = 0.f;
#pragma unroll
            for (int fc = 0; fc < 4; ++fc)
                p += fmaxf(acc[fr][fc][rg] + b1v[fc], 0.f) * w2v[fc];
#pragma unroll
            for (int off = 1; off < 16; off <<= 1)
                p += __shfl_xor(p, off, 64);      // sum over 16 lane-columns (n)
            if (la == 0) part[(fr * 16 + lg * 4 + rg) * 4 + wv] = p;
        }
    }
    __syncthreads();
    if (t < 64) {
        const float sum = part[t * 4 + 0] + part[t * 4 + 1] + part[t * 4 + 2] + part[t * 4 + 3];
        __builtin_nontemporal_store(
            sum, part_ws + ((size_t)nblk * B_DIM + b) * S_LEN + s0 + t);
    }
}

// comp_mean[s] = (1/16) sum_b sigmoid(cb2 + half0[b][s] + half1[b][s]);
// steps_used ≡ 1 (rb<=128-t can never make trunc(rb/(S-t+1))>=2; negative rb clips
// to 1); rb_final = 128-4096 = -3968.
__global__ __launch_bounds__(256) void reduce_comp(const float* __restrict__ part_ws,
                                                   const float* __restrict__ cb2,
                                                   float* __restrict__ out) {
    const int s = blockIdx.x * 256 + threadIdx.x;
    const float c2 = cb2[0];
    float sum = 0.f;
#pragma unroll
    for (int b = 0; b < B_DIM; ++b) {
        const float l = c2 + part_ws[(size_t)b * S_LEN + s]
                           + part_ws[((size_t)B_DIM + b) * S_LEN + s];
        sum += 1.f / (1.f + __expf(-l));
    }
    __builtin_nontemporal_store(sum * (1.f / 16.f), out + OUT_BASE + S_LEN + s);
    __builtin_nontemporal_store(1.0f, out + OUT_BASE + s);
    if (s == 0) __builtin_nontemporal_store(-3968.0f, out + OUT_BASE + 2 * S_LEN);
}

extern "C" void kernel_launch(void* const* d_in, const int* in_sizes, int n_in,
                              void* d_out, int out_size, void* d_ws, size_t ws_size,
                              hipStream_t stream) {
    const float* states = (const float*)d_in[0];
    const float* cW1 = (const float*)d_in[5];
    const float* cb1 = (const float*)d_in[6];
    const float* cW2 = (const float*)d_in[7];
    const float* cb2 = (const float*)d_in[8];
    float* out = (float*)d_out;
    unsigned short* wT = (unsigned short*)d_ws;                 // 1 MB bf16, pre-swizzled
    float* part_ws = (float*)((char*)d_ws + (size_t)D_DIM * H_DIM * 2);  // 512 KB [2][16][4096]

    hipLaunchKernelGGL(prep_transpose, dim3(128), dim3(256), 0, stream, cW1, wT);
    hipLaunchKernelGGL(comp_gemm_kernel, dim3(2048), dim3(256), 0, stream,
                       states, wT, cb1, cW2, out, part_ws);
    hipLaunchKernelGGL(reduce_comp, dim3(16), dim3(256), 0, stream, part_ws, cb2, out);
}

// Round 12
// 175.466 us; speedup vs baseline: 1.3239x; 1.3239x over previous
//
#include <hip/hip_runtime.h>
#include <hip/hip_bf16.h>

typedef short bf8 __attribute__((ext_vector_type(8)));   // 8 bf16 (4 VGPRs)
typedef short bf4 __attribute__((ext_vector_type(4)));   // 4 bf16 (8 B)
typedef float f4 __attribute__((ext_vector_type(4)));
typedef const __attribute__((address_space(1))) void* gvp;
typedef __attribute__((address_space(3))) void* lvp;

#define S_LEN 4096
#define H_DIM 1024
#define D_DIM 512
#define B_DIM 16
#define OUT_BASE ((size_t)B_DIM * S_LEN * H_DIM)

// float -> bf16 bits, round-to-nearest-even
static __device__ __forceinline__ unsigned short f2bf(float f) {
    union { float f; unsigned int u; } c; c.f = f;
    unsigned int u = c.u;
    return (unsigned short)((u + 0x7FFFu + ((u >> 16) & 1u)) >> 16);
}

// cW1 [K=1024][N=512] f32 -> wT[n][chunk 0..31][slot 0..3] bf16 (pitch 2048 B),
// PRE-SWIZZLED: slot sl holds k-slot j = sl ^ ((n>>1)&3). GEMM's linear global_load_lds
// + swizzled ds_read (slot = lg ^ ((la>>1)&3)) recovers k-slot lg; 2-way-bank (free).
__global__ __launch_bounds__(256) void prep_transpose(const float* __restrict__ cW1,
                                                      unsigned short* __restrict__ wT) {
    __shared__ float tile[64][68];
    const int kt = blockIdx.x >> 3;   // 16 tiles of 64 k
    const int nt = blockIdx.x & 7;    // 8 tiles of 64 n
    const int tr = threadIdx.x >> 4;
    const int tc = threadIdx.x & 15;
#pragma unroll
    for (int i = 0; i < 4; ++i) {
        const f4 v = *(const f4*)(cW1 + (size_t)(kt * 64 + i * 16 + tr) * D_DIM + nt * 64 + tc * 4);
        tile[i * 16 + tr][tc * 4 + 0] = v.x;
        tile[i * 16 + tr][tc * 4 + 1] = v.y;
        tile[i * 16 + tr][tc * 4 + 2] = v.z;
        tile[i * 16 + tr][tc * 4 + 3] = v.w;
    }
    __syncthreads();
    const int n_local = threadIdx.x & 63;
    const int q = threadIdx.x >> 6;        // slot 0..3
    const int n = nt * 64 + n_local;
    const int j = q ^ ((n >> 1) & 3);      // data k-slot stored at slot q
    char* wTb = (char*)wT;
#pragma unroll
    for (int c_local = 0; c_local < 2; ++c_local) {   // two 32-k chunks per 64k tile
        const int k0 = c_local * 32 + j * 8;
        bf8 pk;
#pragma unroll
        for (int i = 0; i < 8; ++i) pk[i] = (short)f2bf(tile[k0 + i][n_local]);
        *(bf8*)(wTb + (size_t)n * 2048 + (kt * 2 + c_local) * 64 + q * 16) = pk;
    }
}

// Fused stream+GEMM (R10 GEMM structure + staging-level copy-out).
// M=64 (one b, 64 s) x N=512, BK=32 (32 chunks), 8 waves (1M x 8N), wave 64x64,
// acc[4][4]=64 AGPR, ~120 total regs -> 2 blocks/CU (72 KB LDS also -> 2).
// A staging map (row=t>>3, kq=t&7): one f4/thread, 16-B lane stride -> the fused
// nt copy-out store is per-instruction DENSE (8 rows x 128 B per wave, no holes,
// no write amplification — R11's 2x WRITE came from 32-B-stride holes).
// Counted tail vmcnt(2): retires [st_prev, glA_prev, 4 glB]; keeps [glA, st] flying.
__global__ __launch_bounds__(512, 4) void comp_gemm_kernel(
    const float* __restrict__ states,
    const unsigned short* __restrict__ wT,
    const float* __restrict__ cb1,
    const float* __restrict__ cW2,
    const float* __restrict__ cb2,
    float* __restrict__ out,
    float* __restrict__ part_ws) {
    __shared__ alignas(16) char lds[73728];   // B [2][512][64] @0, A [2][64][64] @65536
    char* ldsB = lds;
    char* ldsA = lds + 65536;

    const int t = threadIdx.x;
    const int lane = t & 63;
    const int wv = t >> 6;                // 0..7 : n-slice [wv*64, +64)
    const int la = lane & 15;
    const int lg = lane >> 4;
    const int gid = blockIdx.x;
    const int b = gid >> 6;
    const int s0 = (gid & 63) * 64;

    // ---- B staging: 4 x global_load_lds(16B/lane)/chunk; linear dest, swizzled src ----
    const char* srcB = (const char*)wT + (size_t)(t >> 2) * 2048 + (t & 3) * 16;
    char* dstB = ldsB + t * 16;
    // B read: row = wv*64 + fc*16 + la, slot = lg ^ ((la>>1)&3)  (2-way, free)
    const char* brd = ldsB + (wv * 64 + la) * 64 + ((lg ^ ((la >> 1) & 3)) * 16);

    // ---- A staging / fused copy-out: (row = t>>3, kq = t&7); one f4 = 16 B per
    // thread at 16-B lane stride -> dense per-instruction store footprint ----
    const int arow = t >> 3;
    const int kq = t & 7;
    const size_t abase = ((size_t)b * S_LEN + s0 + arow) * H_DIM + kq * 4;
    const float* srcA = states + abase;
    float* dstO = out + abase;
    char* dstA = ldsA + arow * 64 + ((((kq >> 1) ^ ((arow >> 2) & 3)) * 2 + (kq & 1)) * 8);
    // A read: row = fr*16 + la, slot = lg ^ (la>>2)  (2-way, free)
    const char* ard = ldsA + la * 64 + ((lg ^ (la >> 2)) * 16);

    f4 acc[4][4];
#pragma unroll
    for (int a = 0; a < 4; ++a)
#pragma unroll
        for (int c = 0; c < 4; ++c) acc[a][c] = f4{0.f, 0.f, 0.f, 0.f};

    auto issueB = [&](int buf_, int ck_) {
#pragma unroll
        for (int i = 0; i < 4; ++i)
            __builtin_amdgcn_global_load_lds((gvp)(srcB + (size_t)i * 128 * 2048 + ck_ * 64),
                                             (lvp)(dstB + buf_ * 32768 + i * 8192), 16, 0, 0);
    };
    auto writeA = [&](int buf_, const f4 a) {
        bf4 p;
        p[0] = (short)f2bf(a.x); p[1] = (short)f2bf(a.y);
        p[2] = (short)f2bf(a.z); p[3] = (short)f2bf(a.w);
        *(bf4*)(dstA + buf_ * 4096) = p;
    };
    auto storeO = [&](int ck_, const f4 a) {
        __builtin_nontemporal_store(a, (f4*)(dstO + ck_ * 32));
    };

    // ---- prologue: A(0)+B(0) -> buf0; A(1) in regs; copy-out A(0) ----
    f4 qa = *(const f4*)(srcA);
    issueB(0, 0);
    f4 qn = *(const f4*)(srcA + 32);
    writeA(0, qa);                                       // pack auto-waits A(0) load
    storeO(0, qa);
    // queue: [4 glB, glA(1), st] -> vmcnt(2) retires glB exactly
    asm volatile("s_waitcnt vmcnt(2) lgkmcnt(0)" ::: "memory");
    __builtin_amdgcn_sched_barrier(0);
    __builtin_amdgcn_s_barrier();
    __builtin_amdgcn_sched_barrier(0);
    qa = qn;

#pragma unroll 1
    for (int ck = 0; ck < 32; ++ck) {
        const int buf = ck & 1;
        if (ck < 31) {
            writeA(buf ^ 1, qa);                         // stage A(ck+1)
            issueB(buf ^ 1, ck + 1);                     // 4 glds -> other buffer
            if (ck < 30) qn = *(const f4*)(srcA + (ck + 2) * 32);   // A(ck+2) prefetch
            storeO(ck + 1, qa);                          // fused copy-out (dense)
            __builtin_amdgcn_sched_barrier(0);
        }
        // compute chunk ck from buf
        bf8 af[4];
#pragma unroll
        for (int fr = 0; fr < 4; ++fr)
            af[fr] = *(const bf8*)(ard + buf * 4096 + fr * 1024);
#pragma unroll
        for (int fc = 0; fc < 4; ++fc) {
            const bf8 bv = *(const bf8*)(brd + buf * 32768 + fc * 1024);
#pragma unroll
            for (int fr = 0; fr < 4; ++fr)
                acc[fr][fc] = __builtin_amdgcn_mfma_f32_16x16x32_bf16(af[fr], bv, acc[fr][fc], 0, 0, 0);
        }
        if (ck < 31) {
            // queue: [glA_old, st_old, 4 glB, (glA_new), st_new]
            if (ck < 30) { asm volatile("s_waitcnt vmcnt(2) lgkmcnt(0)" ::: "memory"); }
            else         { asm volatile("s_waitcnt vmcnt(1) lgkmcnt(0)" ::: "memory"); }
            __builtin_amdgcn_sched_barrier(0);
            __builtin_amdgcn_s_barrier();
            __builtin_amdgcn_sched_barrier(0);
            if (ck < 30) qa = qn;
        }
    }

    // ---- epilogue: relu + dot(cW2) + sigmoid/16 -> per-(b,s) partial ----
    float w2v[4], b1v[4];
#pragma unroll
    for (int fc = 0; fc < 4; ++fc) {
        const int d = wv * 64 + fc * 16 + la;
        w2v[fc] = cW2[d];
        b1v[fc] = cb1[d];
    }
    float* part = (float*)ldsA;   // [64 rows][8 wv] overlays A-buf0 (dead after ck30 barrier)
#pragma unroll
    for (int fr = 0; fr < 4; ++fr) {
#pragma unroll
        for (int rg = 0; rg < 4; ++rg) {
            float p = 0.f;
#pragma unroll
            for (int fc = 0; fc < 4; ++fc)
                p += fmaxf(acc[fr][fc][rg] + b1v[fc], 0.f) * w2v[fc];
#pragma unroll
            for (int off = 1; off < 16; off <<= 1)
                p += __shfl_xor(p, off, 64);      // sum over 16 lane-columns (n)
            if (la == 0) part[(fr * 16 + lg * 4 + rg) * 8 + wv] = p;
        }
    }
    __syncthreads();
    if (t < 64) {
        float sum = cb2[0];
#pragma unroll
        for (int ww = 0; ww < 8; ++ww) sum += part[t * 8 + ww];
        const float sg = 1.f / (1.f + __expf(-sum));
        __builtin_nontemporal_store(sg * (1.f / 16.f), part_ws + (size_t)b * S_LEN + s0 + t);
    }
}

// comp_mean[s] = sum_b partial[b][s]; steps_used ≡ 1 (rb<=128-t can never make
// trunc(rb/(S-t+1))>=2; negative rb clips to 1); rb_final = 128-4096 = -3968.
__global__ __launch_bounds__(256) void reduce_comp(const float* __restrict__ part_ws,
                                                   float* __restrict__ out) {
    const int s = blockIdx.x * 256 + threadIdx.x;
    float sum = 0.f;
#pragma unroll
    for (int b = 0; b < B_DIM; ++b) sum += part_ws[(size_t)b * S_LEN + s];
    __builtin_nontemporal_store(sum, out + OUT_BASE + S_LEN + s);    // comp_mean
    __builtin_nontemporal_store(1.0f, out + OUT_BASE + s);           // steps_used
    if (s == 0) __builtin_nontemporal_store(-3968.0f, out + OUT_BASE + 2 * S_LEN);
}

extern "C" void kernel_launch(void* const* d_in, const int* in_sizes, int n_in,
                              void* d_out, int out_size, void* d_ws, size_t ws_size,
                              hipStream_t stream) {
    const float* states = (const float*)d_in[0];
    const float* cW1 = (const float*)d_in[5];
    const float* cb1 = (const float*)d_in[6];
    const float* cW2 = (const float*)d_in[7];
    const float* cb2 = (const float*)d_in[8];
    float* out = (float*)d_out;
    unsigned short* wT = (unsigned short*)d_ws;                 // 1 MB bf16, pre-swizzled
    float* part_ws = (float*)((char*)d_ws + (size_t)D_DIM * H_DIM * 2);  // 256 KB [16][4096]

    hipLaunchKernelGGL(prep_transpose, dim3(128), dim3(256), 0, stream, cW1, wT);
    hipLaunchKernelGGL(comp_gemm_kernel, dim3(1024), dim3(512), 0, stream,
                       states, wT, cb1, cW2, cb2, out, part_ws);
    hipLaunchKernelGGL(reduce_comp, dim3(16), dim3(256), 0, stream, part_ws, out);
}